// Round 1
// baseline (396.960 us; speedup 1.0000x reference)
//
#include <hip/hip_runtime.h>

// GIN 2-layer via linearity:
//   z1 = (I+A)x ; hid = z1@W1^T + b1
//   z2 = (I+A)z1 ; out = z2@(W2W1)^T + (1+deg)*(W2b1) + b2
// bf16 gathers (fp8 fails accuracy: r4 absmax 4.94 > 2.5). CSR via fixed-
// capacity radix buckets (no hist, no global scan): rpse[node]=(start,end).

#define DFEAT 128
#define BSHIFT 8
#define NB_MAX 512
#define CAP 8192   // per-bucket capacity; mean 4096, 64-sigma safe

typedef __attribute__((ext_vector_type(8))) short short8;
typedef __attribute__((ext_vector_type(4))) float f32x4;

__device__ __forceinline__ float bf2f(unsigned short u) {
    union { unsigned int i; float f; } c;
    c.i = ((unsigned int)u) << 16;
    return c.f;
}
__device__ __forceinline__ unsigned short f2b(float f) {
    union { float f; unsigned int i; } c;
    c.f = f;
    unsigned int u = c.i;
    u = (u + 0x7FFFu + ((u >> 16) & 1u)) >> 16;   // RNE
    return (unsigned short)u;
}

// ---------------- CSR build ----------------

__global__ void init_bcur(int* __restrict__ bcur, int nb) {
    int b = blockIdx.x * 256 + threadIdx.x;
    if (b < nb) bcur[b] = b * CAP;
}

__global__ __launch_bounds__(256) void bucket_scatter(const int* __restrict__ src,
                                                      const int* __restrict__ dst,
                                                      int* __restrict__ bcur,
                                                      int* __restrict__ ebuf, int E) {
    __shared__ int lh[NB_MAX];
    int tid = threadIdx.x;
    for (int i = tid; i < NB_MAX; i += 256) lh[i] = 0;
    __syncthreads();
    int e0 = blockIdx.x * 4096;
    int e1 = min(e0 + 4096, E);
    int s[16], d[16];
    #pragma unroll
    for (int j = 0; j < 16; j++) {
        int e = e0 + tid + 256 * j;
        if (e < e1) { s[j] = src[e]; d[j] = dst[e]; atomicAdd(&lh[d[j] >> BSHIFT], 1); }
    }
    __syncthreads();
    for (int i = tid; i < NB_MAX; i += 256) {
        int c = lh[i];
        lh[i] = c ? atomicAdd(&bcur[i], c) : 0;   // block's base run in bucket i
    }
    __syncthreads();
    #pragma unroll
    for (int j = 0; j < 16; j++) {
        int e = e0 + tid + 256 * j;
        if (e < e1) {
            int b = d[j] >> BSHIFT;
            int p = atomicAdd(&lh[b], 1);
            if (p < (b + 1) * CAP) ebuf[p] = (s[j] << 8) | (d[j] & 255);
        }
    }
}

// one block per bucket (256 nodes): LDS hist + scan + scatter -> rpse, esrc
__global__ __launch_bounds__(256) void build_csr(const int* __restrict__ ebuf,
                                                 const int* __restrict__ bcur,
                                                 int2* __restrict__ rpse,
                                                 int* __restrict__ esrc, int n) {
    __shared__ int hist[256];
    __shared__ int wsum[4];
    __shared__ int woff2[4];
    int tid = threadIdx.x;
    int b = blockIdx.x;
    int nbase = b << BSHIFT;
    int e0 = b * CAP;
    int e1 = min(bcur[b], e0 + CAP);
    hist[tid] = 0;
    __syncthreads();
    for (int e = e0 + tid; e < e1; e += 256)
        atomicAdd(&hist[ebuf[e] & 255], 1);
    __syncthreads();
    int v = hist[tid];
    int lane = tid & 63, wid = tid >> 6;
    int inc = v;
    #pragma unroll
    for (int off = 1; off < 64; off <<= 1) {
        int u = __shfl_up(inc, off, 64);
        if (lane >= off) inc += u;
    }
    if (lane == 63) wsum[wid] = inc;
    __syncthreads();
    if (tid == 0) {
        int run = 0;
        #pragma unroll
        for (int w = 0; w < 4; w++) { woff2[w] = run; run += wsum[w]; }
    }
    __syncthreads();
    int excl = woff2[wid] + inc - v;
    int node = nbase + tid;
    if (node < n) rpse[node] = make_int2(e0 + excl, e0 + excl + v);
    __syncthreads();
    hist[tid] = excl;
    __syncthreads();
    for (int e = e0 + tid; e < e1; e += 256) {
        int le = ebuf[e];
        int p = atomicAdd(&hist[le & 255], 1);
        esrc[e0 + p] = ((unsigned int)le) >> 8;
    }
}

// ---------------- casts / weight prep ----------------

__global__ __launch_bounds__(256) void cast_bf16(const float* __restrict__ x,
                                                 unsigned short* __restrict__ xb, int total4) {
    int i = blockIdx.x * 256 + threadIdx.x;
    if (i >= total4) return;
    float4 v = ((const float4*)x)[i];
    ushort4 o;
    o.x = f2b(v.x); o.y = f2b(v.y); o.z = f2b(v.z); o.w = f2b(v.w);
    ((ushort4*)xb)[i] = o;
}

// block i: Wcb row i = bf16(W2[i,:]@W1), Wb1 row i = bf16(W1[i,:]), w2b1[i]
__global__ __launch_bounds__(128) void prep_w(const float* __restrict__ W1,
                                              const float* __restrict__ W2,
                                              const float* __restrict__ b1,
                                              unsigned short* __restrict__ Wb1,
                                              unsigned short* __restrict__ Wcb,
                                              float* __restrict__ w2b1) {
    __shared__ float red[128];
    int i = blockIdx.x, j = threadIdx.x;
    float s = 0.f;
    #pragma unroll 4
    for (int k = 0; k < 128; k++) s += W2[i * 128 + k] * W1[k * 128 + j];
    Wcb[i * 128 + j] = f2b(s);
    Wb1[i * 128 + j] = f2b(W1[i * 128 + j]);
    red[j] = W2[i * 128 + j] * b1[j];
    __syncthreads();
    if (j == 0) {
        float t = 0.f;
        for (int k = 0; k < 128; k++) t += red[k];
        w2b1[i] = t;
    }
}

// ---------------- aggregation: z_out = z_in + A z_in (bf16 rows) ----------------
// 2 nodes/wave: 32 lanes x ushort4 (8 B) per 256 B row. Edge indices loaded
// once coalesced, broadcast via __shfl; 8 gathers in flight. Gathers use
// 32-bit byte offsets against the uniform base (saddr form): table is
// 25.6 MB so ix*256 + hl*8 < 2^25 always fits.

__global__ __launch_bounds__(256) void agg_bf16(const ushort4* __restrict__ zin4,
                                                const int2* __restrict__ rpse,
                                                const int* __restrict__ esrc,
                                                ushort4* __restrict__ zout4, int n) {
    int node = blockIdx.x * 8 + (threadIdx.x >> 5);
    if (node >= n) return;
    int hl = threadIdx.x & 31;
    int base = threadIdx.x & 32;   // lane base of this half-wave
    int2 se = rpse[node];
    int e0 = se.x, deg = se.y - se.x;

    const char* zb = (const char*)zin4;
    unsigned lb = (unsigned)hl * 8u;

    ushort4 sv = *(const ushort4*)(zb + ((unsigned)node * 256u + lb));
    float a0 = bf2f(sv.x), a1 = bf2f(sv.y), a2 = bf2f(sv.z), a3 = bf2f(sv.w);

    int eidx = (hl < deg) ? esrc[e0 + hl] : 0;
    int m = min(deg, 32);
    int j = 0;
    for (; j + 8 <= m; j += 8) {
        unsigned off[8];
        ushort4 vv[8];
        #pragma unroll
        for (int k = 0; k < 8; k++)
            off[k] = (unsigned)__shfl(eidx, base + j + k) * 256u + lb;
        #pragma unroll
        for (int k = 0; k < 8; k++) vv[k] = *(const ushort4*)(zb + off[k]);
        #pragma unroll
        for (int k = 0; k < 8; k++) {
            a0 += bf2f(vv[k].x); a1 += bf2f(vv[k].y);
            a2 += bf2f(vv[k].z); a3 += bf2f(vv[k].w);
        }
    }
    for (; j < m; j++) {
        unsigned off = (unsigned)__shfl(eidx, base + j) * 256u + lb;
        ushort4 v = *(const ushort4*)(zb + off);
        a0 += bf2f(v.x); a1 += bf2f(v.y); a2 += bf2f(v.z); a3 += bf2f(v.w);
    }
    for (int e = e0 + 32; e < e0 + deg; e++) {   // rare deg>32 tail
        unsigned off = (unsigned)esrc[e] * 256u + lb;
        ushort4 v = *(const ushort4*)(zb + off);
        a0 += bf2f(v.x); a1 += bf2f(v.y); a2 += bf2f(v.z); a3 += bf2f(v.w);
    }

    ushort4 o;
    o.x = f2b(a0); o.y = f2b(a1); o.z = f2b(a2); o.w = f2b(a3);
    zout4[(size_t)node * 32 + hl] = o;
}

// ---------------- MFMA GEMMs ----------------

__global__ __launch_bounds__(256) void gemm_hid(const unsigned short* __restrict__ Z,
                                                const unsigned short* __restrict__ Wb,
                                                const float* __restrict__ bias,
                                                float* __restrict__ out, int n) {
    int wid = threadIdx.x >> 6, lane = threadIdx.x & 63;
    int base = blockIdx.x * 64 + wid * 16;
    int m = lane & 15, quad = lane >> 4;
    const short* zp = (const short*)Z + (size_t)(base + m) * 128 + quad * 8;
    short8 a0 = *(const short8*)(zp);
    short8 a1 = *(const short8*)(zp + 32);
    short8 a2 = *(const short8*)(zp + 64);
    short8 a3 = *(const short8*)(zp + 96);
    f32x4 acc[8];
    #pragma unroll
    for (int c = 0; c < 8; c++) acc[c] = (f32x4){0.f, 0.f, 0.f, 0.f};
    #pragma unroll
    for (int c = 0; c < 8; c++) {
        const short* wp = (const short*)Wb + (size_t)(c * 16 + m) * 128 + quad * 8;
        short8 b0 = *(const short8*)(wp);
        short8 b1v = *(const short8*)(wp + 32);
        short8 b2v = *(const short8*)(wp + 64);
        short8 b3v = *(const short8*)(wp + 96);
        acc[c] = __builtin_amdgcn_mfma_f32_16x16x32_bf16(a0, b0, acc[c], 0, 0, 0);
        acc[c] = __builtin_amdgcn_mfma_f32_16x16x32_bf16(a1, b1v, acc[c], 0, 0, 0);
        acc[c] = __builtin_amdgcn_mfma_f32_16x16x32_bf16(a2, b2v, acc[c], 0, 0, 0);
        acc[c] = __builtin_amdgcn_mfma_f32_16x16x32_bf16(a3, b3v, acc[c], 0, 0, 0);
    }
    int row0 = base + quad * 4;
    #pragma unroll
    for (int c = 0; c < 8; c++) {
        float bb = bias[c * 16 + m];
        #pragma unroll
        for (int r = 0; r < 4; r++) {
            int node = row0 + r;
            if (node < n) out[(size_t)node * 128 + c * 16 + m] = acc[c][r] + bb;
        }
    }
}

__global__ __launch_bounds__(256) void gemm_out(const unsigned short* __restrict__ Z,
                                                const unsigned short* __restrict__ Wb,
                                                const float* __restrict__ w2b1,
                                                const float* __restrict__ bias2,
                                                const int2* __restrict__ rpse,
                                                float* __restrict__ out, int n) {
    int wid = threadIdx.x >> 6, lane = threadIdx.x & 63;
    int base = blockIdx.x * 64 + wid * 16;
    int m = lane & 15, quad = lane >> 4;
    const short* zp = (const short*)Z + (size_t)(base + m) * 128 + quad * 8;
    short8 a0 = *(const short8*)(zp);
    short8 a1 = *(const short8*)(zp + 32);
    short8 a2 = *(const short8*)(zp + 64);
    short8 a3 = *(const short8*)(zp + 96);
    f32x4 acc[8];
    #pragma unroll
    for (int c = 0; c < 8; c++) acc[c] = (f32x4){0.f, 0.f, 0.f, 0.f};
    #pragma unroll
    for (int c = 0; c < 8; c++) {
        const short* wp = (const short*)Wb + (size_t)(c * 16 + m) * 128 + quad * 8;
        short8 b0 = *(const short8*)(wp);
        short8 b1v = *(const short8*)(wp + 32);
        short8 b2v = *(const short8*)(wp + 64);
        short8 b3v = *(const short8*)(wp + 96);
        acc[c] = __builtin_amdgcn_mfma_f32_16x16x32_bf16(a0, b0, acc[c], 0, 0, 0);
        acc[c] = __builtin_amdgcn_mfma_f32_16x16x32_bf16(a1, b1v, acc[c], 0, 0, 0);
        acc[c] = __builtin_amdgcn_mfma_f32_16x16x32_bf16(a2, b2v, acc[c], 0, 0, 0);
        acc[c] = __builtin_amdgcn_mfma_f32_16x16x32_bf16(a3, b3v, acc[c], 0, 0, 0);
    }
    int row0 = base + quad * 4;
    float degf[4];
    #pragma unroll
    for (int r = 0; r < 4; r++) {
        int node = row0 + r;
        if (node < n) {
            int2 se = rpse[node];
            degf[r] = (float)(1 + se.y - se.x);
        } else degf[r] = 0.f;
    }
    #pragma unroll
    for (int c = 0; c < 8; c++) {
        int col = c * 16 + m;
        float wb = w2b1[col];
        float bb = bias2[col];
        #pragma unroll
        for (int r = 0; r < 4; r++) {
            int node = row0 + r;
            if (node < n) out[(size_t)node * 128 + col] = acc[c][r] + degf[r] * wb + bb;
        }
    }
}

// ---------------- launch ----------------

extern "C" void kernel_launch(void* const* d_in, const int* in_sizes, int n_in,
                              void* d_out, int out_size, void* d_ws, size_t ws_size,
                              hipStream_t stream) {
    const float* x  = (const float*)d_in[0];
    const int*   ei = (const int*)d_in[1];
    const float* W1 = (const float*)d_in[2];
    const float* b1 = (const float*)d_in[3];
    const float* W2 = (const float*)d_in[4];
    const float* b2 = (const float*)d_in[5];

    const int n = in_sizes[0] / DFEAT;   // 100000
    const int E = in_sizes[1] / 2;       // 1600000
    const int* src = ei;
    const int* dst = ei + E;
    const int nbuckets = (n + (1 << BSHIFT) - 1) >> BSHIFT;   // 391

    float* out = (float*)d_out;
    float* hid = out + (size_t)n * DFEAT;

    // workspace (65 MB): z1b | R2 (ebuf -> xb -> z2b, disjoint lifetimes) | CSR | weights
    char* w = (char*)d_ws;
    const size_t szB = (size_t)n * DFEAT * sizeof(unsigned short);   // 25.6 MB
    unsigned short* z1b = (unsigned short*)w;
    char* R2 = w + szB;
    int* ebuf = (int*)R2;                        // nbuckets*CAP ints = 12.8 MB
    unsigned short* xb = (unsigned short*)R2;    // 25.6 MB (after build_csr)
    unsigned short* z2b = (unsigned short*)R2;   // 25.6 MB (after agg1)
    int* esrc = (int*)(w + 2 * szB);             // nbuckets*CAP = 12.8 MB
    int2* rpse = (int2*)(esrc + (size_t)nbuckets * CAP);
    int* bcur = (int*)(rpse + n);
    char* wp = (char*)(bcur + NB_MAX);
    unsigned short* Wb1 = (unsigned short*)wp;
    unsigned short* Wcb = Wb1 + DFEAT * DFEAT;
    float* w2b1 = (float*)(Wcb + DFEAT * DFEAT);

    // CSR build (capacity buckets: no hist, no global scan)
    init_bcur<<<(nbuckets + 255) / 256, 256, 0, stream>>>(bcur, nbuckets);
    bucket_scatter<<<(E + 4095) / 4096, 256, 0, stream>>>(src, dst, bcur, ebuf, E);
    build_csr<<<nbuckets, 256, 0, stream>>>(ebuf, bcur, rpse, esrc, n);

    // casts + weight prep (cast after build_csr: xb aliases ebuf)
    cast_bf16<<<(n * 32 + 255) / 256, 256, 0, stream>>>(x, xb, n * 32);
    prep_w<<<128, 128, 0, stream>>>(W1, W2, b1, Wb1, Wcb, w2b1);

    const int agg_blocks = (n + 7) / 8;
    const int gemm_blocks = (n + 63) / 64;

    // layer 1
    agg_bf16<<<agg_blocks, 256, 0, stream>>>((const ushort4*)xb, rpse, esrc,
                                             (ushort4*)z1b, n);
    gemm_hid<<<gemm_blocks, 256, 0, stream>>>(z1b, Wb1, b1, hid, n);

    // layer 2 (z2b overwrites xb region — xb dead after agg1)
    agg_bf16<<<agg_blocks, 256, 0, stream>>>((const ushort4*)z1b, rpse, esrc,
                                             (ushort4*)z2b, n);
    gemm_out<<<gemm_blocks, 256, 0, stream>>>(z2b, Wcb, w2b1, b2, rpse, out, n);
}